// Round 3
// baseline (838.258 us; speedup 1.0000x reference)
//
#include <hip/hip_runtime.h>
#include <math.h>

#define BB 16384
#define CC 10000
#define DD 256
#define N4 (CC / 4)                 // 2500
#define ROWS_PER_BLOCK 4
#define NBLK (BB / ROWS_PER_BLOCK)  // 4096
#define COEF 1.0f
#define CLAMP_MIN 1e-12f
#define CLAMP_MAX 1.0e12f

// One wave (64 lanes) per batch row; 4 rows per 256-thread block.
__global__ __launch_bounds__(256) void center_ce_kernel(
    const float* __restrict__ embeddings,
    const float* __restrict__ outputs,
    const int*   __restrict__ target,
    const float* __restrict__ centers,
    float*       __restrict__ partials)
{
    const int tid  = threadIdx.x;
    const int lane = tid & 63;
    const int wave = tid >> 6;
    const int row  = blockIdx.x * ROWS_PER_BLOCK + wave;
    const int t    = target[row];

    // ---- center loss: lane i covers dims 4i..4i+3 (DD == 256 == 64 lanes * 4)
    const float4* ep = (const float4*)(embeddings + (size_t)row * DD);
    const float4* cp = (const float4*)(centers    + (size_t)t   * DD);
    float4 e = ep[lane];
    float4 c = cp[lane];
    float dx = e.x - c.x, dy = e.y - c.y, dz = e.z - c.z, dw = e.w - c.w;
    float dsq = dx * dx + dy * dy + dz * dz + dw * dw;

    // ---- online softmax over outputs[row, :], float4 loads
    // 2-way ILP: two independent (m,s) accumulators, branchless rescale.
    const float4* rowp = (const float4*)(outputs + (size_t)row * CC);
    float m1 = -INFINITY, s1 = 0.0f;
    float m2 = -INFINITY, s2 = 0.0f;
    int idx = lane;
    for (; idx + 64 < N4; idx += 128) {
        float4 a = rowp[idx];
        float4 b = rowp[idx + 64];
        float mxa = fmaxf(fmaxf(a.x, a.y), fmaxf(a.z, a.w));
        float mxb = fmaxf(fmaxf(b.x, b.y), fmaxf(b.z, b.w));
        float na = fmaxf(m1, mxa);
        float nb = fmaxf(m2, mxb);
        s1 = s1 * __expf(m1 - na)
           + __expf(a.x - na) + __expf(a.y - na) + __expf(a.z - na) + __expf(a.w - na);
        s2 = s2 * __expf(m2 - nb)
           + __expf(b.x - nb) + __expf(b.y - nb) + __expf(b.z - nb) + __expf(b.w - nb);
        m1 = na;
        m2 = nb;
    }
    for (; idx < N4; idx += 64) {   // at most one leftover float4
        float4 a = rowp[idx];
        float mxa = fmaxf(fmaxf(a.x, a.y), fmaxf(a.z, a.w));
        float na = fmaxf(m1, mxa);
        s1 = s1 * __expf(m1 - na)
           + __expf(a.x - na) + __expf(a.y - na) + __expf(a.z - na) + __expf(a.w - na);
        m1 = na;
    }
    // merge the two accumulators (m1 is always finite: >=19 iterations)
    float m = fmaxf(m1, m2);
    float s = s1 * __expf(m1 - m) + s2 * __expf(m2 - m);

    // ---- wave shuffle reduction of (m, s) and dsq
    for (int off = 32; off > 0; off >>= 1) {
        float om = __shfl_down(m, off, 64);
        float os = __shfl_down(s, off, 64);
        float od = __shfl_down(dsq, off, 64);
        float nm = fmaxf(m, om);
        s = s * __expf(m - nm) + os * __expf(om - nm);
        m = nm;
        dsq += od;
    }

    __shared__ float sl[ROWS_PER_BLOCK];
    if (lane == 0) {
        float x_t  = outputs[(size_t)row * CC + t];
        float dist = fminf(fmaxf(dsq, CLAMP_MIN), CLAMP_MAX);
        float nll  = -(x_t - m - __logf(s));
        sl[wave] = dist * COEF + nll;
    }
    __syncthreads();
    if (tid == 0) {
        float acc = 0.0f;
        #pragma unroll
        for (int w = 0; w < ROWS_PER_BLOCK; ++w) acc += sl[w];
        partials[blockIdx.x] = acc;   // plain store, no atomics
    }
}

__global__ __launch_bounds__(256) void reduce_kernel(
    const float* __restrict__ partials, float* __restrict__ out)
{
    const int tid = threadIdx.x;
    float acc = 0.0f;
    for (int i = tid; i < NBLK; i += 256) acc += partials[i];  // 16 each
    for (int off = 32; off > 0; off >>= 1) acc += __shfl_down(acc, off, 64);
    __shared__ float sw[4];
    if ((tid & 63) == 0) sw[tid >> 6] = acc;
    __syncthreads();
    if (tid == 0) out[0] = (sw[0] + sw[1] + sw[2] + sw[3]) * (1.0f / (float)BB);
}

extern "C" void kernel_launch(void* const* d_in, const int* in_sizes, int n_in,
                              void* d_out, int out_size, void* d_ws, size_t ws_size,
                              hipStream_t stream) {
    const float* embeddings = (const float*)d_in[0];
    const float* outputs    = (const float*)d_in[1];
    const int*   target     = (const int*)  d_in[2];
    const float* centers    = (const float*)d_in[3];
    float* partials = (float*)d_ws;            // 4096 floats = 16 KB of ws
    float* out      = (float*)d_out;

    hipLaunchKernelGGL(center_ce_kernel, dim3(NBLK), dim3(256), 0, stream,
                       embeddings, outputs, target, centers, partials);
    hipLaunchKernelGGL(reduce_kernel, dim3(1), dim3(256), 0, stream,
                       partials, out);
}